// Round 3
// baseline (280.048 us; speedup 1.0000x reference)
//
#include <hip/hip_runtime.h>
#include <hip/hip_bf16.h>

#define B_ 4
#define S_ 2048
#define E_ 1024
#define H_ 8
#define D_ 128

using f16x8 = __attribute__((ext_vector_type(8))) _Float16;
using f32x4 = __attribute__((ext_vector_type(4))) float;

__device__ __forceinline__ ushort f2h_bits(float f) {
    union { _Float16 h; ushort u; } cv; cv.h = (_Float16)f; return cv.u;
}
__device__ __forceinline__ f16x8 pack8(const float* __restrict__ p) {
    float4 f0 = *(const float4*)p;
    float4 f1 = *(const float4*)(p + 4);
    f16x8 r;
    r[0] = (_Float16)f0.x; r[1] = (_Float16)f0.y;
    r[2] = (_Float16)f0.z; r[3] = (_Float16)f0.w;
    r[4] = (_Float16)f1.x; r[5] = (_Float16)f1.y;
    r[6] = (_Float16)f1.z; r[7] = (_Float16)f1.w;
    return r;
}

// direct global->LDS DMA, 16B per lane; LDS dest is wave-uniform base + lane*16
__device__ __forceinline__ void gll16(const ushort* g, ushort* l) {
    __builtin_amdgcn_global_load_lds(
        (const __attribute__((address_space(1))) unsigned int*)g,
        (__attribute__((address_space(3))) unsigned int*)l, 16, 0, 0);
}

// ---------------- K/V projection ----------------
// grid: (B*S/64, H), block 256 (4 waves, 16 rows each). 17 KB LDS -> all
// 1024 blocks resident (4/CU), 2x the wave-parallelism of the old version.
// K out: [B,H,S,D] fp16, pre-swizzled: within each s-row, 8-elem chunk at
//   position p holds logical chunk p ^ (s&7).
// V out TRANSPOSED [B,H,D,S] fp16, pre-swizzled within each 64-s block:
//   position p holds logical chunk p ^ (d&7)  (low-3-bit XOR, block-local).
__global__ __launch_bounds__(256) void kv_proj(
    const float* __restrict__ seq,
    const float* __restrict__ Wk, const float* __restrict__ Wv,
    const float* __restrict__ bk, const float* __restrict__ bv,
    ushort* __restrict__ ko, ushort* __restrict__ vo)
{
    __shared__ ushort T[128 * 68];   // 17408 B; Tk view [64][136] / Tv view [128][68]
    const int m0 = blockIdx.x * 64, h = blockIdx.y;
    const int tid = threadIdx.x, lane = tid & 63, w = tid >> 6;
    const int l16 = lane & 15, quad = lane >> 4;

    // A-frags: A[m=lane&15][k=quad*8+j], rows m0 + w*16 + l16
    f16x8 a[4];
    #pragma unroll
    for (int ks = 0; ks < 4; ++ks)
        a[ks] = pack8(&seq[(size_t)(m0 + w * 16 + l16) * E_
                           + h * D_ + ks * 32 + quad * 8]);

    // ---- K ----
    {
        const float* W = Wk + (size_t)h * D_ * D_;
        f32x4 acc[8];
        #pragma unroll
        for (int nt = 0; nt < 8; ++nt) { f32x4 z = {0.f,0.f,0.f,0.f}; acc[nt] = z; }
        #pragma unroll
        for (int ks = 0; ks < 4; ++ks)
            #pragma unroll
            for (int nt = 0; nt < 8; ++nt) {
                f16x8 bfr = pack8(&W[(size_t)(nt * 16 + l16) * D_ + ks * 32 + quad * 8]);
                acc[nt] = __builtin_amdgcn_mfma_f32_16x16x32_f16(
                    a[ks], bfr, acc[nt], 0, 0, 0);
            }
        #pragma unroll
        for (int nt = 0; nt < 8; ++nt) {
            int o = nt * 16 + l16;
            float bias = bk[h * D_ + o];
            #pragma unroll
            for (int r = 0; r < 4; ++r) {
                int row = w * 16 + quad * 4 + r;
                T[row * 136 + (o ^ (quad << 3))] = f2h_bits(acc[nt][r] + bias);
            }
        }
    }
    __syncthreads();
    // K stores (coalesced b128, apply attn pre-swizzle)
    #pragma unroll
    for (int i = 0; i < 4; ++i) {
        int idx = tid + i * 256;
        int row = idx >> 4, c8 = (idx & 15) * 8;
        int lk = c8 ^ ((row & 7) << 3);
        uint4 dk = *(uint4*)&T[row * 136 + (lk ^ (((row >> 2) & 3) << 3))];
        int m = m0 + row, bi = m >> 11, s = m & (S_ - 1);
        *(uint4*)&ko[(((size_t)bi * H_ + h) * S_ + s) * D_ + c8] = dk;
    }
    __syncthreads();
    // ---- V ----
    {
        const float* W = Wv + (size_t)h * D_ * D_;
        f32x4 acc[8];
        #pragma unroll
        for (int nt = 0; nt < 8; ++nt) { f32x4 z = {0.f,0.f,0.f,0.f}; acc[nt] = z; }
        #pragma unroll
        for (int ks = 0; ks < 4; ++ks)
            #pragma unroll
            for (int nt = 0; nt < 8; ++nt) {
                f16x8 bfr = pack8(&W[(size_t)(nt * 16 + l16) * D_ + ks * 32 + quad * 8]);
                acc[nt] = __builtin_amdgcn_mfma_f32_16x16x32_f16(
                    a[ks], bfr, acc[nt], 0, 0, 0);
            }
        #pragma unroll
        for (int nt = 0; nt < 8; ++nt) {
            int o = nt * 16 + l16;
            float bias = bv[h * D_ + o];
            #pragma unroll
            for (int r = 0; r < 4; ++r) {
                int row = w * 16 + quad * 4 + r;     // s_local
                T[o * 68 + row] = f2h_bits(acc[nt][r] + bias);
            }
        }
    }
    __syncthreads();
    // V stores: [d][s_local 0..63], position chunk c holds logical c^(d&7)
    #pragma unroll
    for (int i = 0; i < 4; ++i) {
        int idx = tid + i * 256;
        int d = idx >> 3, c = idx & 7;
        uint4 dv = *(uint4*)&T[d * 68 + ((c ^ (d & 7)) << 3)];
        int bi = m0 >> 11, s0 = (m0 & (S_ - 1)) + c * 8;
        *(uint4*)&vo[(((size_t)bi * H_ + h) * D_ + d) * S_ + s0] = dv;
    }
}

// ---------------- Flash attention ----------------
// grid: (S/128, H, B), block 512 (8 waves, 16 Q-rows each). BN = 64.
// LDS = K[2][64x128] + V[2][128x64] + P[128x64] = 81920 B -> 2 blocks/CU
// (16 waves/CU, 4/SIMD): two independent blocks overlap each other's
// barrier/softmax latency. 1 barrier/iter; K,V double-buffered via
// global_load_lds DMA (prefetch j+1 at top of iter j, drained by the
// end-of-iter barrier). All swizzles XOR at 16B-chunk granularity.
__global__ __launch_bounds__(512) void attn(
    const float* __restrict__ seq, const float* __restrict__ Wq,
    const float* __restrict__ bq,
    const ushort* __restrict__ kg, const ushort* __restrict__ vtg,
    float* __restrict__ out)
{
    constexpr int NT = S_ / 64;                      // 32 K/V tiles
    __shared__ alignas(16) ushort Kbuf[2][64 * 128]; // 32 KB (also Q scratch)
    __shared__ alignas(16) ushort Vbuf[2][128 * 64]; // 32 KB
    __shared__ alignas(16) ushort Pbuf[128 * 64];    // 16 KB, P^T[q][s]

    const int m0 = blockIdx.x * 128;
    const int h = blockIdx.y, bi = blockIdx.z;
    const int bh = bi * H_ + h;
    const int tid = threadIdx.x, lane = tid & 63, w = tid >> 6;
    const int l16 = lane & 15, quad = lane >> 4;
    const int swz = l16 & 7;
    const ushort* kbase = kg + (size_t)bh * S_ * D_;   // 64-row tile = 16 KB contiguous
    const ushort* vbase = vtg + (size_t)bh * D_ * S_;  // row stride S_
    const float qscale = 0.35355339059327373f * 1.4426950408889634f; // 1/sqrt(8)*log2e

    // ---- prologue: DMA V tile 0 (Vbuf untouched by Q scratch) ----
    #pragma unroll
    for (int c = 0; c < 2; ++c) {
        int i = w * 2 + c;
        gll16(vbase + (size_t)(i * 8 + (lane >> 3)) * S_ + (lane & 7) * 8,
              &Vbuf[0][0] + i * 512);
    }

    // ---- Phase 0: Q tile = X Wq^T + bq (scaled), transposed through Kbuf ----
    ushort* const Qs = &Kbuf[0][0];                  // [128][128] scratch
    {
        f16x8 xa[4];
        #pragma unroll
        for (int ks = 0; ks < 4; ++ks)
            xa[ks] = pack8(&seq[((size_t)bi * S_ + m0 + w * 16 + l16) * E_
                                + h * D_ + ks * 32 + quad * 8]);
        f32x4 qacc[8];
        #pragma unroll
        for (int nt = 0; nt < 8; ++nt) { f32x4 z = {0.f,0.f,0.f,0.f}; qacc[nt] = z; }
        const float* W = Wq + (size_t)h * D_ * D_;
        #pragma unroll
        for (int ks = 0; ks < 4; ++ks)
            #pragma unroll
            for (int nt = 0; nt < 8; ++nt) {
                f16x8 bfr = pack8(&W[(size_t)(nt * 16 + l16) * D_ + ks * 32 + quad * 8]);
                qacc[nt] = __builtin_amdgcn_mfma_f32_16x16x32_f16(
                    xa[ks], bfr, qacc[nt], 0, 0, 0);
            }
        #pragma unroll
        for (int nt = 0; nt < 8; ++nt) {
            int o = nt * 16 + l16;
            float bias = bq[h * D_ + o];
            #pragma unroll
            for (int r = 0; r < 4; ++r) {
                int row = w * 16 + quad * 4 + r;
                Qs[row * 128 + (o ^ (quad << 3))] =
                    f2h_bits((qacc[nt][r] + bias) * qscale);
            }
        }
    }
    __syncthreads();   // Q visible (V0 DMA also drained)

    // qf[ks]: Q[q=w*16+l16][d=ks*32+quad*8..+7]
    f16x8 qf[4];
    #pragma unroll
    for (int ks = 0; ks < 4; ++ks)
        qf[ks] = *(const f16x8*)&Qs[(w * 16 + l16) * 128
                                    + ks * 32 + ((quad ^ (l16 >> 2)) << 3)];
    __syncthreads();   // all qf reads done before K0 DMA overwrites scratch

    // ---- DMA K tile 0 ----
    #pragma unroll
    for (int c = 0; c < 2; ++c) {
        int i = w * 2 + c;
        gll16(kbase + i * 512 + lane * 8, &Kbuf[0][0] + i * 512);
    }

    f32x4 o_acc[8];    // O^T: d = nt*16+quad*4+r, q = w*16+l16
    #pragma unroll
    for (int nt = 0; nt < 8; ++nt) { f32x4 z = {0.f,0.f,0.f,0.f}; o_acc[nt] = z; }
    float m_prev = -1e30f, l_lane = 0.f;

    __syncthreads();   // K0 drained

    ushort* const prow = &Pbuf[(w * 16 + l16) * 64];

    for (int j = 0; j < NT; ++j) {
        const int cur = j & 1;
        const ushort* KL = &Kbuf[cur][0];
        const ushort* VL = &Vbuf[cur][0];

        // prefetch tile j+1 (drains at this iter's end barrier)
        if (j + 1 < NT) {
            const ushort* kt = kbase + (size_t)(j + 1) * 64 * 128;
            const ushort* vt = vbase + (j + 1) * 64;
            ushort* kd = &Kbuf[cur ^ 1][0];
            ushort* vd = &Vbuf[cur ^ 1][0];
            #pragma unroll
            for (int c = 0; c < 2; ++c) {
                int i = w * 2 + c;
                gll16(kt + i * 512 + lane * 8, kd + i * 512);
                gll16(vt + (size_t)(i * 8 + (lane >> 3)) * S_ + (lane & 7) * 8,
                      vd + i * 512);
            }
        }

        // S^T = K Q^T: sacc[nt]: s = nt*16+quad*4+r, q = w*16+l16
        f32x4 sacc[4];
        #pragma unroll
        for (int nt = 0; nt < 4; ++nt) { f32x4 z = {0.f,0.f,0.f,0.f}; sacc[nt] = z; }
        __builtin_amdgcn_s_setprio(1);
        #pragma unroll
        for (int ks = 0; ks < 4; ++ks)
            #pragma unroll
            for (int nt = 0; nt < 4; ++nt) {
                f16x8 kf = *(const f16x8*)&KL[(nt * 16 + l16) * 128
                                              + (((ks * 4 + quad) ^ swz) << 3)];
                sacc[nt] = __builtin_amdgcn_mfma_f32_16x16x32_f16(
                    kf, qf[ks], sacc[nt], 0, 0, 0);
            }
        __builtin_amdgcn_s_setprio(0);

        // online softmax — 16 lane-local s-values
        uint2 pkw[4];
        {
            float mx = fmaxf(fmaxf(sacc[0][0], sacc[0][1]), fmaxf(sacc[0][2], sacc[0][3]));
            #pragma unroll
            for (int nt = 1; nt < 4; ++nt)
                mx = fmaxf(mx, fmaxf(fmaxf(sacc[nt][0], sacc[nt][1]),
                                     fmaxf(sacc[nt][2], sacc[nt][3])));
            mx = fmaxf(mx, __shfl_xor(mx, 16));
            mx = fmaxf(mx, __shfl_xor(mx, 32));
            // defer-max: rescale only when max grew past THR=8 (log2 domain, P<=256)
            if (__any(mx > m_prev + 8.0f)) {
                float mnew  = fmaxf(m_prev, mx);
                float alpha = exp2f(m_prev - mnew);
                #pragma unroll
                for (int nt = 0; nt < 8; ++nt)
                    #pragma unroll
                    for (int r = 0; r < 4; ++r) o_acc[nt][r] *= alpha;
                l_lane *= alpha;
                m_prev = mnew;
            }
            #pragma unroll
            for (int nt = 0; nt < 4; ++nt) {
                float e0 = exp2f(sacc[nt][0] - m_prev);
                float e1 = exp2f(sacc[nt][1] - m_prev);
                float e2 = exp2f(sacc[nt][2] - m_prev);
                float e3 = exp2f(sacc[nt][3] - m_prev);
                auto p01 = __builtin_amdgcn_cvt_pkrtz(e0, e1);
                auto p23 = __builtin_amdgcn_cvt_pkrtz(e2, e3);
                // denominator sees the same f16 quantization as the numerator
                l_lane += (float)p01[0] + (float)p01[1] + (float)p23[0] + (float)p23[1];
                pkw[nt] = make_uint2(__builtin_bit_cast(uint, p01),
                                     __builtin_bit_cast(uint, p23));
            }
        }

        // P^T[q][s] writes: b64 at 16B-group (2nt+(quad>>1))^swz, half quad&1
        #pragma unroll
        for (int nt = 0; nt < 4; ++nt) {
            int G = 2 * nt + (quad >> 1);
            *(uint2*)&prow[((G ^ swz) << 3) + ((quad & 1) << 2)] = pkw[nt];
        }

        // O^T += V^T P^T  (A = Vt frag, B = own-row P^T frag)
        __builtin_amdgcn_s_setprio(1);
        #pragma unroll
        for (int ks = 0; ks < 2; ++ks) {
            f16x8 pb = *(const f16x8*)&prow[((ks * 4 + quad) ^ swz) << 3];
            #pragma unroll
            for (int nt = 0; nt < 8; ++nt) {
                f16x8 vf = *(const f16x8*)&VL[(nt * 16 + l16) * 64
                                              + (((ks * 4 + quad) ^ swz) << 3)];
                o_acc[nt] = __builtin_amdgcn_mfma_f32_16x16x32_f16(
                    vf, pb, o_acc[nt], 0, 0, 0);
            }
        }
        __builtin_amdgcn_s_setprio(0);

        __syncthreads();   // reads of tile j done; tile j+1 DMA drained
    }

    // epilogue: complete l across quads, O/l, float4 stores to fp32 [B,S,E]
    {
        float l = l_lane;
        l += __shfl_xor(l, 16);
        l += __shfl_xor(l, 32);
        float rinv = 1.0f / l;
        const int q = m0 + w * 16 + l16;
        #pragma unroll
        for (int nt = 0; nt < 8; ++nt) {
            float4 o;
            o.x = o_acc[nt][0] * rinv;
            o.y = o_acc[nt][1] * rinv;
            o.z = o_acc[nt][2] * rinv;
            o.w = o_acc[nt][3] * rinv;
            *(float4*)&out[((size_t)bi * S_ + q) * E_ + h * D_ + nt * 16 + quad * 4] = o;
        }
    }
}

extern "C" void kernel_launch(void* const* d_in, const int* in_sizes, int n_in,
                              void* d_out, int out_size, void* d_ws, size_t ws_size,
                              hipStream_t stream) {
    const float* seq = (const float*)d_in[0];
    const float* Wq  = (const float*)d_in[1];
    const float* Wk  = (const float*)d_in[2];
    const float* Wv  = (const float*)d_in[3];
    const float* bq  = (const float*)d_in[4];
    const float* bk  = (const float*)d_in[5];
    const float* bv  = (const float*)d_in[6];

    const size_t per = (size_t)B_ * H_ * S_ * D_;      // 8M elements
    if (ws_size < 2 * per * sizeof(ushort)) return;    // need 32 MB
    ushort* kws  = (ushort*)d_ws;          // [B,H,S,D]   pre-swizzled
    ushort* vtws = kws + per;              // [B,H,D,S]   pre-swizzled

    kv_proj<<<dim3(B_ * S_ / 64, H_), 256, 0, stream>>>(
        seq, Wk, Wv, bk, bv, kws, vtws);
    attn<<<dim3(S_ / 128, H_, B_), 512, 0, stream>>>(
        seq, Wq, bq, kws, vtws, (float*)d_out);
}